// Round 12
// baseline (36.180 us; speedup 1.0000x reference)
//
#include <hip/hip_runtime.h>

// Fused: out[b, c*9+d] = sum_hw fcn[b,c,hw] * kern[c*9+d, hw], row-L2-normalized.
// B=4096, C=128, D=9, HW=64, all fp32. One kernel; fcn read once; out written once.
//
// Occupancy push (R11 = 16 waves/CU @ 31.6us, 74% of achievable BW):
//  - RB=2 rows/block, grid 2048 = 8 blocks/CU available
//  - register diet: stream raw results to LDS tile PER channel-iter (the final
//    tile write just moves inside the loop) -> keep[9] transient, no keep[4][9];
//    f0/f1 = 2 rows x 2 = 16 regs. Natural ~60-75 VGPR -> 28-32 waves/CU.
//  - __launch_bounds__(256,2): cap 128 (toolchain decode: cap ~= 256/N; N>=3
//    means <=85..64 regs -> spill risk, R5/R8/R10). Trust natural fit.
//  - sumsq accumulated on the fly; lanes l>=RB contribute zeros.
// reduce8 = 3 DPP adds (quad_perm xor1/xor2 + row_half_mirror), zero DS ops.
// Spill tripwire: WRITE_SIZE must stay ~18.5 MB.

constexpr int B_TOT = 4096;
constexpr int C_CH  = 128;
constexpr int D_EMB = 9;
constexpr int THREADS = 256;
constexpr int GPB = 32;   // concurrent channels (groups) per block
constexpr int NCH = 4;    // channel iterations per group
constexpr int RB  = 2;    // rows per block
constexpr int ROWF = C_CH * D_EMB;   // 1152 floats per output row

__device__ __forceinline__ float reduce8_hw(float p) {
    // sum over the 8-lane group, VALU-only DPP (R7-proven)
    p += __int_as_float(__builtin_amdgcn_mov_dpp(__float_as_int(p), 0xB1,  0xf, 0xf, true)); // xor1
    p += __int_as_float(__builtin_amdgcn_mov_dpp(__float_as_int(p), 0x4E,  0xf, 0xf, true)); // xor2
    p += __int_as_float(__builtin_amdgcn_mov_dpp(__float_as_int(p), 0x141, 0xf, 0xf, true)); // xor4 (row_half_mirror)
    return p;
}

__global__ __launch_bounds__(THREADS, 2)
void esenc_fused(const float* __restrict__ fcn,
                 const float* __restrict__ kern,
                 float* __restrict__ out) {
    __shared__ __align__(16) float tile[RB * ROWF];   // 9216 B
    __shared__ float red[4 * RB];                      // 4 waves x 2 rows
    __shared__ float invn[RB];

    const int tid = threadIdx.x;
    const int l   = tid & 7;        // hw-slice lane; rows 0..1 kept by lanes 0..1
    const int g   = tid >> 3;       // group 0..31
    const int w   = tid >> 6;       // wave 0..3
    const unsigned b0 = blockIdx.x * RB;

    const float4* kern4 = (const float4*)kern;
    const float4* f4    = (const float4*)fcn;

    float s = 0.0f;                 // row-l sumsq partial (this thread's channels)

#pragma unroll
    for (int ch = 0; ch < NCH; ++ch) {
        const unsigned c = (unsigned)(ch * GPB + g);

        // fcn rows resident: 2 rows x 2 float4 (read once, 16 VGPR)
        float4 f0[RB], f1[RB];
#pragma unroll
        for (int r = 0; r < RB; ++r) {
            const unsigned fb = ((b0 + (unsigned)r) * C_CH + c) * 16u;
            f0[r] = f4[fb + l];
            f1[r] = f4[fb + 8u + l];
        }

        float keep[D_EMB] = {};     // transient; lanes l>=RB stay zero
#pragma unroll
        for (int d = 0; d < D_EMB; ++d) {
            const unsigned kb = (c * D_EMB + (unsigned)d) * 16u;
            const float4 k0 = kern4[kb + l];     // transient: 8 VGPR
            const float4 k1 = kern4[kb + 8u + l];
#pragma unroll
            for (int r = 0; r < RB; ++r) {
                float t;
                t = f0[r].x * k0.x;
                t = fmaf(f0[r].y, k0.y, t);
                t = fmaf(f0[r].z, k0.z, t);
                t = fmaf(f0[r].w, k0.w, t);
                t = fmaf(f1[r].x, k1.x, t);
                t = fmaf(f1[r].y, k1.y, t);
                t = fmaf(f1[r].z, k1.z, t);
                t = fmaf(f1[r].w, k1.w, t);
                t = reduce8_hw(t);
                if (l == r) keep[d] = t;
            }
        }

        // stream raw results to LDS (lanes l<RB), accumulate sumsq on the fly
        if (l < RB) {
            const int c_i = ch * GPB + g;
#pragma unroll
            for (int d = 0; d < D_EMB; ++d) {
                tile[l * ROWF + c_i * D_EMB + d] = keep[d];
                s = fmaf(keep[d], keep[d], s);
            }
        }
    }

    // row sumsq: reduce over the wave's 8 groups (lanes l>=RB carry 0)
    s += __shfl_xor(s, 8,  64);
    s += __shfl_xor(s, 16, 64);
    s += __shfl_xor(s, 32, 64);
    if ((tid & 63) < RB) red[w * RB + l] = s;
    __syncthreads();
    if (tid < RB)
        invn[tid] = 1.0f / sqrtf(red[tid] + red[RB + tid] + red[2 * RB + tid]
                                 + red[3 * RB + tid] + 1e-10f);
    __syncthreads();

    // coalesced store: 2 contiguous rows = 576 float4
    const float4* t4 = (const float4*)tile;
    float4* o4 = (float4*)(out + (size_t)b0 * ROWF);
#pragma unroll
    for (int j = 0; j < (RB * ROWF / 4 + THREADS - 1) / THREADS; ++j) {
        const int i = tid + j * THREADS;
        if (i < RB * ROWF / 4) {
            const float inv = invn[i / (ROWF / 4)];
            float4 v = t4[i];
            v.x *= inv; v.y *= inv; v.z *= inv; v.w *= inv;
            o4[i] = v;
        }
    }
}

extern "C" void kernel_launch(void* const* d_in, const int* in_sizes, int n_in,
                              void* d_out, int out_size, void* d_ws, size_t ws_size,
                              hipStream_t stream) {
    const float* fcn  = (const float*)d_in[0];   // [4096,128,8,8] f32
    const float* kern = (const float*)d_in[1];   // [1,1152,8,8]  f32
    float* out = (float*)d_out;                  // [4096,1152]   f32

    dim3 grid(B_TOT / RB), block(THREADS);       // 2048 blocks
    hipLaunchKernelGGL(esenc_fused, grid, block, 0, stream, fcn, kern, out);
}

// Round 13
// 31.993 us; speedup vs baseline: 1.1309x; 1.1309x over previous
//
#include <hip/hip_runtime.h>

// Fused: out[b, c*9+d] = sum_hw fcn[b,c,hw] * kern[c*9+d, hw], row-L2-normalized.
// B=4096, C=128, D=9, HW=64, all fp32. One kernel; fcn read once; out written once.
//
// R11 geometry (best, 31.6us = 78% of BW floor): block = 4 rows x 128 ch,
// 256 thr = 32 groups x 8 lanes, NCH=4, grid 1024 = 16 waves/CU (VGPR 65..128).
// R13 changes (traffic-neutral, latency-hiding):
//  - stream keep[] to LDS tile per channel-iter (R12 trick): keep[4][9] -> keep[9]
//  - spend freed regs on explicit 1-ahead fcn prefetch (nxt 8xfloat4): next
//    iter's HBM loads issue before current iter's 9-d compute -> latency hidden
//  - natural ~100 VGPR < 128 cap of __launch_bounds__(256,2). NEVER N>=3
//    (toolchain decode: cap ~= 256/N; R5/R8/R10 spilled at 64-reg cap).
//  - occupancy is a step function (m69): <=64 regs -> 32 w/CU; 65..128 -> 16.
//    R12 proved chasing 32 w/CU via RB=2 doubles kern L2 traffic: net loss.
// reduce8 = 3 DPP adds (quad_perm xor1/xor2 + row_half_mirror), zero DS ops.
// Spill tripwire: WRITE_SIZE must stay ~18.5 MB.

constexpr int B_TOT = 4096;
constexpr int C_CH  = 128;
constexpr int D_EMB = 9;
constexpr int THREADS = 256;
constexpr int GPB = 32;   // concurrent channels (groups) per block
constexpr int NCH = 4;    // channel iterations per group
constexpr int RB  = 4;    // rows per block
constexpr int ROWF = C_CH * D_EMB;   // 1152 floats per output row

__device__ __forceinline__ float reduce8_hw(float p) {
    // sum over the 8-lane group, VALU-only DPP (R7-proven)
    p += __int_as_float(__builtin_amdgcn_mov_dpp(__float_as_int(p), 0xB1,  0xf, 0xf, true)); // xor1
    p += __int_as_float(__builtin_amdgcn_mov_dpp(__float_as_int(p), 0x4E,  0xf, 0xf, true)); // xor2
    p += __int_as_float(__builtin_amdgcn_mov_dpp(__float_as_int(p), 0x141, 0xf, 0xf, true)); // xor4 (row_half_mirror)
    return p;
}

__global__ __launch_bounds__(THREADS, 2)
void esenc_fused(const float* __restrict__ fcn,
                 const float* __restrict__ kern,
                 float* __restrict__ out) {
    __shared__ __align__(16) float tile[RB * ROWF];   // 18432 B
    __shared__ float red[4 * RB];                      // 4 waves x 4 rows
    __shared__ float invn[RB];

    const int tid = threadIdx.x;
    const int l   = tid & 7;        // hw-slice lane; rows 0..3 kept by lanes 0..3
    const int g   = tid >> 3;       // group 0..31
    const int w   = tid >> 6;       // wave 0..3
    const unsigned b0 = blockIdx.x * RB;

    const float4* kern4 = (const float4*)kern;
    const float4* f4    = (const float4*)fcn;

    float s = 0.0f;                 // row-l sumsq partial over this thread's channels

    // current-iter fcn rows (32 VGPR)
    float4 p0[RB], p1[RB];
#pragma unroll
    for (int r = 0; r < RB; ++r) {
        const unsigned fb = ((b0 + (unsigned)r) * C_CH + (unsigned)g) * 16u;
        p0[r] = f4[fb + l];
        p1[r] = f4[fb + 8u + l];
    }

#pragma unroll
    for (int ch = 0; ch < NCH; ++ch) {
        const unsigned c = (unsigned)(ch * GPB + g);

        // prefetch next channel-iter's fcn rows (issue before compute; 32 VGPR)
        float4 n0[RB], n1[RB];
        if (ch + 1 < NCH) {
            const unsigned cn = c + (unsigned)GPB;
#pragma unroll
            for (int r = 0; r < RB; ++r) {
                const unsigned fb = ((b0 + (unsigned)r) * C_CH + cn) * 16u;
                n0[r] = f4[fb + l];
                n1[r] = f4[fb + 8u + l];
            }
        }

        float keep[D_EMB] = {};     // transient; lanes l>=RB stay zero
#pragma unroll
        for (int d = 0; d < D_EMB; ++d) {
            const unsigned kb = (c * D_EMB + (unsigned)d) * 16u;
            const float4 k0 = kern4[kb + l];     // transient: 8 VGPR, L2-hot
            const float4 k1 = kern4[kb + 8u + l];
#pragma unroll
            for (int r = 0; r < RB; ++r) {
                float t;
                t = p0[r].x * k0.x;
                t = fmaf(p0[r].y, k0.y, t);
                t = fmaf(p0[r].z, k0.z, t);
                t = fmaf(p0[r].w, k0.w, t);
                t = fmaf(p1[r].x, k1.x, t);
                t = fmaf(p1[r].y, k1.y, t);
                t = fmaf(p1[r].z, k1.z, t);
                t = fmaf(p1[r].w, k1.w, t);
                t = reduce8_hw(t);
                if (l == r) keep[d] = t;
            }
        }

        // stream raw results to LDS (lanes l<RB), accumulate sumsq on the fly
        if (l < RB) {
#pragma unroll
            for (int d = 0; d < D_EMB; ++d) {
                tile[l * ROWF + (int)c * D_EMB + d] = keep[d];
                s = fmaf(keep[d], keep[d], s);
            }
        }

        // rotate prefetch -> current (register renames, static indices)
        if (ch + 1 < NCH) {
#pragma unroll
            for (int r = 0; r < RB; ++r) { p0[r] = n0[r]; p1[r] = n1[r]; }
        }
    }

    // row sumsq: reduce over the wave's 8 groups (lanes l>=RB carry 0)
    s += __shfl_xor(s, 8,  64);
    s += __shfl_xor(s, 16, 64);
    s += __shfl_xor(s, 32, 64);
    if ((tid & 63) < RB) red[w * RB + l] = s;
    __syncthreads();
    if (tid < RB)
        invn[tid] = 1.0f / sqrtf(red[tid] + red[RB + tid] + red[2 * RB + tid]
                                 + red[3 * RB + tid] + 1e-10f);
    __syncthreads();

    // coalesced store: 4 contiguous rows = 1152 float4
    const float4* t4 = (const float4*)tile;
    float4* o4 = (float4*)(out + (size_t)b0 * ROWF);
#pragma unroll
    for (int j = 0; j < (RB * ROWF / 4 + THREADS - 1) / THREADS; ++j) {
        const int i = tid + j * THREADS;
        if (i < RB * ROWF / 4) {
            const float inv = invn[i / (ROWF / 4)];
            float4 v = t4[i];
            v.x *= inv; v.y *= inv; v.z *= inv; v.w *= inv;
            o4[i] = v;
        }
    }
}

extern "C" void kernel_launch(void* const* d_in, const int* in_sizes, int n_in,
                              void* d_out, int out_size, void* d_ws, size_t ws_size,
                              hipStream_t stream) {
    const float* fcn  = (const float*)d_in[0];   // [4096,128,8,8] f32
    const float* kern = (const float*)d_in[1];   // [1,1152,8,8]  f32
    float* out = (float*)d_out;                  // [4096,1152]   f32

    dim3 grid(B_TOT / RB), block(THREADS);       // 1024 blocks
    hipLaunchKernelGGL(esenc_fused, grid, block, 0, stream, fcn, kern, out);
}